// Round 5
// baseline (174.710 us; speedup 1.0000x reference)
//
#include <hip/hip_runtime.h>
#include <math.h>

// Problem constants
#define V    4
#define T    4
#define NSRC 100000   // NS
#define NHX  12288    // NH
#define E    100000
#define H    64
#define VT   16       // (v,t') edge types
#define NP   5        // 4 t-planes + 1 deg_in count plane

// fused scatter decomposition
#define DQ   4             // dst quarters
#define DR   (NHX/DQ)      // 3072 bins per quarter
#define DRP  (DR+1)        // padded plane stride
#define SC   8             // edge chunks (512 blocks -> 2 blocks/CU, 32 waves/CU)
#define SE   (E/SC)        // 12500

// deg_out histogram: u8 packed, 4 bins per u32 word
#define RCH   2            // src ranges (50% in-range)
#define RBINS (NSRC/RCH)   // 50000 bins
#define RW    (RBINS/4)    // 12500 words = 50 KB LDS
#define HF    16           // edge slices (512 blocks -> 2 blocks/CU)
#define HE    (E/HF)       // 6250

#define NPB  8             // nodes per epilogue block

// ---------------------------------------------------------------------------
// K0: transpose x[v][t][s] -> x4[v][s] = {t=0..3}, nan_to_num folded in.
// ---------------------------------------------------------------------------
__global__ void transpose_kernel(const float* __restrict__ x,
                                 float4* __restrict__ x4) {
    const int v = blockIdx.y;
    const int s = blockIdx.x * 256 + threadIdx.x;
    if (s >= NSRC) return;
    const float* xr = x + (size_t)v * T * NSRC + s;
    float a0 = xr[0], a1 = xr[NSRC], a2 = xr[2 * NSRC], a3 = xr[3 * NSRC];
    float4 r;
    r.x = (a0 == a0) ? a0 : 0.0f;
    r.y = (a1 == a1) ? a1 : 0.0f;
    r.z = (a2 == a2) ? a2 : 0.0f;
    r.w = (a3 == a3) ? a3 : 0.0f;
    x4[(size_t)v * NSRC + s] = r;
}

// ---------------------------------------------------------------------------
// K1: deg_out partial histograms, u8 quads packed in u32 LDS words.
// grid (RCH, HF, VT). Block owns src range [lo,lo+50000), scans 6250 edges.
// Per-slice per-src count <= total degree (~10 max) << 255 -> no overflow.
// ---------------------------------------------------------------------------
__global__ void __launch_bounds__(1024)
cnt_kernel(const int* __restrict__ src, unsigned int* __restrict__ cnt_part) {
    const int rg = blockIdx.x, hf = blockIdx.y, vt = blockIdx.z;
    const int lo = rg * RBINS;
    __shared__ unsigned int pack[RW];           // 50 KB
    for (int i = threadIdx.x; i < RW; i += 1024) pack[i] = 0u;
    __syncthreads();
    const int* s_row = src + vt * E + hf * HE;
    for (int e = threadIdx.x; e < HE; e += 1024) {
        const unsigned r = (unsigned)(s_row[e] - lo);
        if (r < RBINS) atomicAdd(&pack[r >> 2], 1u << ((r & 3) * 8));
    }
    __syncthreads();
    unsigned int* outp = cnt_part + ((size_t)hf * VT + vt) * (NSRC / 4) + rg * RW;
    for (int i = threadIdx.x; i < RW; i += 1024) outp[i] = pack[i];
}

// ---------------------------------------------------------------------------
// K2: ns[vt][s] = rsqrt(max(deg_out,1)). Unpack u8 fields per slice BEFORE
// summing (no carry risk), write float4 coalesced.
// ---------------------------------------------------------------------------
__global__ void nsfin_kernel(const unsigned int* __restrict__ cnt_part,
                             float4* __restrict__ ns4) {
    const int vt = blockIdx.y;
    const int wd = blockIdx.x * 256 + threadIdx.x;
    if (wd >= NSRC / 4) return;
    unsigned c0 = 0, c1 = 0, c2 = 0, c3 = 0;
#pragma unroll
    for (int hf = 0; hf < HF; ++hf) {
        const unsigned w = cnt_part[((size_t)hf * VT + vt) * (NSRC / 4) + wd];
        c0 += w & 0xFFu; c1 += (w >> 8) & 0xFFu;
        c2 += (w >> 16) & 0xFFu; c3 += w >> 24;
    }
    float4 r;
    r.x = rsqrtf(fmaxf((float)c0, 1.0f));
    r.y = rsqrtf(fmaxf((float)c1, 1.0f));
    r.z = rsqrtf(fmaxf((float)c2, 1.0f));
    r.w = rsqrtf(fmaxf((float)c3, 1.0f));
    ns4[(size_t)vt * (NSRC / 4) + wd] = r;
}

// ---------------------------------------------------------------------------
// K3: fused scatter. grid 512 = 8 XCD * 2 vt * 4 dq * 8 c, 1024 thr.
// 2 blocks/CU (2x61KB LDS) -> 32 waves/CU. 2-edge ILP batch per iteration:
// both gathers in flight before the LDS atomic chains.
// XCD k sees only vt=2k,2k+1 (one v): x4 row 1.6MB + 2 ns rows 0.8MB < L2.
// ---------------------------------------------------------------------------
__global__ void __launch_bounds__(1024)
scatter_kernel(const float4* __restrict__ x4, const int* __restrict__ src,
               const int* __restrict__ dst, const float* __restrict__ ns,
               float* __restrict__ part) {
    const int b  = blockIdx.x;            // 0..511
    const int k  = b & 7;                 // XCD
    const int j  = b >> 3;                // 0..63
    const int vt = 2 * k + (j & 1);
    const int r2 = j >> 1;                // 0..31
    const int dq = r2 & 3;
    const int c  = r2 >> 2;               // 0..7
    const int v  = vt >> 2;
    const int dlo = dq * DR;

    __shared__ float agg[NP * DRP];       // 60 KB
    for (int i = threadIdx.x; i < NP * DRP; i += 1024) agg[i] = 0.0f;
    __syncthreads();

    const int*    s_row  = src + vt * E + c * SE;
    const int*    d_row  = dst + vt * E + c * SE;
    const float*  ns_row = ns + (size_t)vt * NSRC;
    const float4* x_row  = x4 + (size_t)v * NSRC;

    for (int e = threadIdx.x; e < SE; e += 2048) {
        const int eB = e + 1024;
        const int sA = s_row[e];
        const unsigned rA = (unsigned)(d_row[e] - dlo);
        int sB = 0; unsigned rB = 0xFFFFFFFFu;
        if (eB < SE) { sB = s_row[eB]; rB = (unsigned)(d_row[eB] - dlo); }

        float4 xA; float nA = 0.0f;
        float4 xB; float nB = 0.0f;
        const bool okA = rA < DR, okB = rB < DR;
        if (okA) { xA = x_row[sA]; nA = ns_row[sA]; }
        if (okB) { xB = x_row[sB]; nB = ns_row[sB]; }

        if (okA) {
            atomicAdd(&agg[0 * DRP + rA], xA.x * nA);
            atomicAdd(&agg[1 * DRP + rA], xA.y * nA);
            atomicAdd(&agg[2 * DRP + rA], xA.z * nA);
            atomicAdd(&agg[3 * DRP + rA], xA.w * nA);
            atomicAdd(&agg[4 * DRP + rA], 1.0f);      // deg_in (exact in f32)
        }
        if (okB) {
            atomicAdd(&agg[0 * DRP + rB], xB.x * nB);
            atomicAdd(&agg[1 * DRP + rB], xB.y * nB);
            atomicAdd(&agg[2 * DRP + rB], xB.z * nB);
            atomicAdd(&agg[3 * DRP + rB], xB.w * nB);
            atomicAdd(&agg[4 * DRP + rB], 1.0f);
        }
    }
    __syncthreads();

    float* base = part + ((size_t)(c * VT + vt) * NP) * NHX + dlo;
    for (int i = threadIdx.x; i < NP * DR; i += 1024) {
        const int p = i / DR, q = i - p * DR;
        base[(size_t)p * NHX + q] = agg[p * DRP + q];
    }
}

// ---------------------------------------------------------------------------
// K4: fused reduce + epilogue. Block handles NPB=8 nodes.
// ---------------------------------------------------------------------------
__global__ void epilogue_kernel(const float* __restrict__ part,
                                const float* __restrict__ Wm,
                                const float* __restrict__ bm,
                                float* __restrict__ out) {
    const int n0  = blockIdx.x * NPB;
    const int tid = threadIdx.x;
    __shared__ float sW[VT * H];
    __shared__ float sb[VT * H];
    __shared__ float sraw[VT][NP][NPB];
    __shared__ float sv[VT][T][NPB];

    for (int i = tid; i < VT * H; i += 256) { sW[i] = Wm[i]; sb[i] = bm[i]; }
    for (int w = tid; w < VT * NP * NPB; w += 256) {   // 640 items
        const int n  = w & (NPB - 1);
        const int p  = (w >> 3) % NP;
        const int vt = w / (NP * NPB);
        float s = 0.0f;
#pragma unroll
        for (int c = 0; c < SC; ++c)
            s += part[(((size_t)(c * VT + vt)) * NP + p) * NHX + n0 + n];
        sraw[vt][p][n] = s;
    }
    __syncthreads();
    for (int w = tid; w < VT * T * NPB; w += 256) {    // 512 items
        const int n  = w & (NPB - 1);
        const int t  = (w >> 3) & 3;
        const int vt = w >> 5;
        sv[vt][t][n] = sraw[vt][t][n] * rsqrtf(fmaxf(sraw[vt][NP - 1][n], 1.0f));
    }
    __syncthreads();

    const int v  = tid >> 6;
    const int t  = (tid >> 4) & 3;
    const int hb = (tid & 15) * 4;
    float4 Wr[4], Br[4];
#pragma unroll
    for (int tp = 0; tp < 4; ++tp) {
        const int wi = (v * 4 + tp) * H + hb;
        Wr[tp] = *(const float4*)&sW[wi];
        Br[tp] = *(const float4*)&sb[wi];
    }
#pragma unroll
    for (int n = 0; n < NPB; ++n) {
        float4 o = make_float4(0.f, 0.f, 0.f, 0.f);
#pragma unroll
        for (int tp = 0; tp < 4; ++tp) {
            const float s = sv[v * 4 + tp][t][n];
            float a;
            a = fmaf(s, Wr[tp].x, Br[tp].x); o.x += (a > 0.f) ? a : 0.01f * a;
            a = fmaf(s, Wr[tp].y, Br[tp].y); o.y += (a > 0.f) ? a : 0.01f * a;
            a = fmaf(s, Wr[tp].z, Br[tp].z); o.z += (a > 0.f) ? a : 0.01f * a;
            a = fmaf(s, Wr[tp].w, Br[tp].w); o.w += (a > 0.f) ? a : 0.01f * a;
        }
        ((float4*)(out + (size_t)(n0 + n) * (V * T * H)))[tid] = o;
    }
}

// ---------------------------------------------------------------------------
extern "C" void kernel_launch(void* const* d_in, const int* in_sizes, int n_in,
                              void* d_out, int out_size, void* d_ws, size_t ws_size,
                              hipStream_t stream) {
    const float* x   = (const float*)d_in[0];   // [V,T,NS]
    const float* Wm  = (const float*)d_in[1];   // [V,T,H]
    const float* bm  = (const float*)d_in[2];   // [V,T,H]
    const int*   src = (const int*)d_in[3];     // [V,T,E]
    const int*   dst = (const int*)d_in[4];     // [V,T,E]
    float* out = (float*)d_out;                 // [NH,V,T,H]

    // workspace (44.3 MB, every region fully overwritten -> no memset):
    //   [x4: V*NSRC float4 6.4MB][ns: VT*NSRC f32 6.4MB][part: SC*VT*NP*NHX 31.5MB]
    // cnt partials (HF*VT*NSRC/4 u32 = 25.6MB) alias part: written K1, read K2,
    // fully overwritten K3 -- stream-ordered, no hazard.
    char* ws = (char*)d_ws;
    float4* x4 = (float4*)ws;
    size_t off = (size_t)V * NSRC * sizeof(float4);
    float* ns = (float*)(ws + off);
    off += (size_t)VT * NSRC * sizeof(float);
    float* part = (float*)(ws + off);
    unsigned int* cnt_part = (unsigned int*)(ws + off);

    transpose_kernel<<<dim3((NSRC + 255) / 256, V), 256, 0, stream>>>(x, x4);
    cnt_kernel<<<dim3(RCH, HF, VT), 1024, 0, stream>>>(src, cnt_part);
    nsfin_kernel<<<dim3((NSRC / 4 + 255) / 256, VT), 256, 0, stream>>>(cnt_part, (float4*)ns);
    scatter_kernel<<<DQ * SC * VT, 1024, 0, stream>>>(x4, src, dst, ns, part);
    epilogue_kernel<<<NHX / NPB, 256, 0, stream>>>(part, Wm, bm, out);
}